// Round 13
// baseline (363.250 us; speedup 1.0000x reference)
//
#include <hip/hip_runtime.h>

// 7x7-window local attention, B=1, C=512, H=W=56, HEADS=8, dkh=64.
// Inputs FP32, output FP32 (round-12 finding: identical absmax 3.195 across
// two schedules == correct values mis-packed as bf16; "2.390625 bf16-exact"
// was a %.6e formatting artifact; harness doc: out dtype = reference's fp32).
// Reshape untangling: m = c2*3136 + x*56 + y = x'*3584 + y'*64 + d;
// group g = m/64: ch = h*64 + g/49, strip sp = (g%49)*64 + d, p = i*7+j.

#define HWSP 3136   // 56*56
#define NPAD 3844   // 62*62

__global__ void bias_kernel(const float* __restrict__ hp,
                            const float* __restrict__ wp,
                            float* __restrict__ biasT) {
    int t = threadIdx.x;
    if (t < 49) {
        int i = t / 7, j = t - i * 7;
        float s = 0.f;
        for (int c = 0; c < 256; ++c) {
            s += hp[c * 7 + i];
            s += wp[c * 7 + j];
        }
        biasT[t] = s;
    }
}

// out[m_local, s] = sum_c W[chBase+m_local, c] * in[c, s] + b[chBase+m_local]
// z=0: N=3136 (q, direct), z=1/2: N=3844 (k/v on zero-padded 62x62 grid).
__global__ __launch_bounds__(256) void conv_kernel(
    const float* __restrict__ x,
    const float* __restrict__ qw, const float* __restrict__ qb,
    const float* __restrict__ kw, const float* __restrict__ kb,
    const float* __restrict__ vw, const float* __restrict__ vb,
    float* __restrict__ Q, float* __restrict__ Kp, float* __restrict__ Vp,
    int chBase) {

    const int z = blockIdx.z;
    const float* W;
    const float* Bb;
    float* Out;
    int N;
    bool padded;
    if (z == 0)      { W = qw; Bb = qb; Out = Q;  N = HWSP; padded = false; }
    else if (z == 1) { W = kw; Bb = kb; Out = Kp; N = NPAD; padded = true; }
    else             { W = vw; Bb = vb; Out = Vp; N = NPAD; padded = true; }

    const int nBase = blockIdx.x * 64;
    if (nBase >= N) return;
    const int mBase = blockIdx.y * 64;

    __shared__ float As[32][68];
    __shared__ float Bs[32][68];

    const int tid = threadIdx.x;
    const int tx = tid & 15, ty = tid >> 4;

    float acc[4][4] = {};

    for (int k0 = 0; k0 < 512; k0 += 32) {
        #pragma unroll
        for (int u = 0; u < 8; ++u) {
            int idx = tid + u * 256;
            int kk = idx & 31, mm = idx >> 5;
            As[kk][mm] = W[(size_t)(chBase + mBase + mm) * 512 + k0 + kk];
        }
        #pragma unroll
        for (int u = 0; u < 8; ++u) {
            int idx = tid + u * 256;
            int nn = idx & 63, kk = idx >> 6;
            int s = nBase + nn;
            int cch = k0 + kk;
            float v = 0.f;
            if (s < N) {
                if (!padded) {
                    v = x[cch * HWSP + s];
                } else {
                    int rr = s / 62, cc = s - rr * 62;
                    int xr = rr - 3, xc = cc - 3;
                    if ((unsigned)xr < 56u && (unsigned)xc < 56u)
                        v = x[cch * HWSP + xr * 56 + xc];
                }
            }
            Bs[kk][nn] = v;
        }
        __syncthreads();
        #pragma unroll
        for (int k = 0; k < 32; ++k) {
            float4 a = *(const float4*)&As[k][ty * 4];
            float4 b = *(const float4*)&Bs[k][tx * 4];
            acc[0][0] += a.x * b.x; acc[0][1] += a.x * b.y; acc[0][2] += a.x * b.z; acc[0][3] += a.x * b.w;
            acc[1][0] += a.y * b.x; acc[1][1] += a.y * b.y; acc[1][2] += a.y * b.z; acc[1][3] += a.y * b.w;
            acc[2][0] += a.z * b.x; acc[2][1] += a.z * b.y; acc[2][2] += a.z * b.z; acc[2][3] += a.z * b.w;
            acc[3][0] += a.w * b.x; acc[3][1] += a.w * b.y; acc[3][2] += a.w * b.z; acc[3][3] += a.w * b.w;
        }
        __syncthreads();
    }

    #pragma unroll
    for (int i = 0; i < 4; ++i) {
        int m = mBase + ty * 4 + i;
        float bb = Bb[chBase + m];
        #pragma unroll
        for (int j = 0; j < 4; ++j) {
            int s = nBase + tx * 4 + j;
            if (s < N) Out[(size_t)m * N + s] = acc[i][j] + bb;
        }
    }
}

// one wave per (head, group-of-64-m); heads [hBase, hBase+nH) in this slice
__global__ __launch_bounds__(256) void attn_kernel(
    const float* __restrict__ Q, const float* __restrict__ Kp,
    const float* __restrict__ Vp, const float* __restrict__ biasT,
    float* __restrict__ out, int hBase) {

    __shared__ float q_s[4][64];
    __shared__ int   b_s[4][64];
    __shared__ float w_s[4][64];

    const int tid = threadIdx.x;
    const int warp = tid >> 6, lane = tid & 63;
    const int G2 = blockIdx.x * 4 + warp;
    const int hLoc = G2 / 3136, g = G2 - hLoc * 3136;
    const int h = hBase + hLoc;
    const int chLoc = hLoc * 64 + g / 49;
    const int sb = (g % 49) * 64;
    const int sp = sb + lane;
    const int r = sp / 56, c2 = sp - r * 56;
    const int base = r * 62 + c2;

    const float qv = Q[(size_t)chLoc * HWSP + sp];
    float qs = qv;
    #pragma unroll
    for (int off = 32; off; off >>= 1) qs += __shfl_xor(qs, off, 64);

    q_s[warp][lane] = qv;
    b_s[warp][lane] = base;
    __syncthreads();

    const int p = (lane < 49) ? lane : 0;
    const int pi = p / 7, pj = p - pi * 7;
    const float* Kc = Kp + (size_t)chLoc * NPAD + pi * 62 + pj;
    float qk = 0.f;
    #pragma unroll 8
    for (int d = 0; d < 64; ++d) qk += q_s[warp][d] * Kc[b_s[warp][d]];
    qk += qs * biasT[p];

    float val = (lane < 49) ? qk : -1e30f;
    float mx = val;
    #pragma unroll
    for (int off = 32; off; off >>= 1) mx = fmaxf(mx, __shfl_xor(mx, off, 64));
    float e = (lane < 49) ? __expf(val - mx) : 0.f;
    float se = e;
    #pragma unroll
    for (int off = 32; off; off >>= 1) se += __shfl_xor(se, off, 64);
    w_s[warp][lane] = e / se;
    __syncthreads();

    const float* Vc = Vp + (size_t)chLoc * NPAD + base;
    float acc = 0.f;
    #pragma unroll
    for (int i = 0; i < 7; ++i)
        #pragma unroll
        for (int j = 0; j < 7; ++j)
            acc += w_s[warp][i * 7 + j] * Vc[i * 62 + j];

    out[(size_t)h * 200704 + g * 64 + lane] = acc;   // FP32 output
}

extern "C" void kernel_launch(void* const* d_in, const int* in_sizes, int n_in,
                              void* d_out, int out_size, void* d_ws, size_t ws_size,
                              hipStream_t stream) {
    const float* x  = (const float*)d_in[0];
    const float* qw = (const float*)d_in[1];
    const float* qb = (const float*)d_in[2];
    const float* kw = (const float*)d_in[3];
    const float* kb = (const float*)d_in[4];
    const float* vw = (const float*)d_in[5];
    const float* vb = (const float*)d_in[6];
    const float* hp = (const float*)d_in[7];
    const float* wp = (const float*)d_in[8];
    float* out = (float*)d_out;

    float* ws    = (float*)d_ws;
    float* biasT = ws;
    float* Q     = ws + 64;

    const size_t needA = (size_t)(64 + 512 * HWSP + 2 * 512 * NPAD) * 4;

    bias_kernel<<<1, 64, 0, stream>>>(hp, wp, biasT);

    if (ws_size >= needA) {
        // Tier A: full staging, single pass (round-10/12 identical absmax
        // proves this footprint is not corrupted => ws_size sufficient).
        float* Kp = Q  + (size_t)512 * HWSP;
        float* Vp = Kp + (size_t)512 * NPAD;
        conv_kernel<<<dim3(61, 8, 3), 256, 0, stream>>>(x, qw, qb, kw, kb, vw, vb,
                                                        Q, Kp, Vp, 0);
        attn_kernel<<<6272, 256, 0, stream>>>(Q, Kp, Vp, biasT, out, 0);
    } else {
        // Tier C fallback: per-head slices (2.77 MB)
        float* Kp = Q  + (size_t)64 * HWSP;
        float* Vp = Kp + (size_t)64 * NPAD;
        for (int h = 0; h < 8; ++h) {
            conv_kernel<<<dim3(61, 1, 3), 256, 0, stream>>>(x, qw, qb, kw, kb, vw, vb,
                                                            Q, Kp, Vp, h * 64);
            attn_kernel<<<784, 256, 0, stream>>>(Q, Kp, Vp, biasT, out, h);
        }
    }
}